// Round 7
// baseline (411.977 us; speedup 1.0000x reference)
//
#include <hip/hip_runtime.h>

// v: [E, 64, 3] f32, k: [E, 8, 16] f32, q: [N, 8, 16] f32, dst: [E] i32
// out: [N, 64, 3] f32.  H=8 heads, T=16, 8 value channels/head, D=3.
//
// Structure:
//  (A) edge-major: stream k at full BW, gather q (25.6MB, L3-hot, 16x reuse),
//      write logits edge-major (lgE stays L3-resident), bucket-append eids.
//  (B) L3-tiled gather: 1536 all-resident blocks; each wave owns 9 nodes
//      (accumulators in VGPRs). v is processed in 10 sequential tiles:
//      warm(t+1) streams the next tile into the memory-side Infinity Cache
//      while gather(t) randomly reads the current tile from L3. DRAM sees v
//      exactly once, sequentially -- sidestepping the ~3 TB/s random wall.
#define HH 8
#define DCAP 64    // per-node edge cap (Poisson(16): P(deg>64) ~ 2e-18)
#define PN 9       // nodes per wave
#define NBLK 1536  // 6 blocks/CU x 256 CUs: all co-resident => loose lockstep
#define NTILE 10   // ~61 MB per v tile; 3 tiles in flight < 256 MB L3

static constexpr float SCALE = 0.08838834764831843f;  // 1/sqrt(8*16)

typedef float vf4 __attribute__((ext_vector_type(4)));
struct f3 {
  float x, y, z;
};  // stride-12 -> global_load_dwordx3

// Pass A: 8 lanes per edge. Stream k nontemporal; gather q; lgE[e*8+h]
// coalesced write; one bucket atomic per edge.
__global__ __launch_bounds__(256) void edge_logits_kernel(
    const float* __restrict__ k, const float* __restrict__ q,
    const int* __restrict__ dst, int* __restrict__ cursor,
    int* __restrict__ eid, float* __restrict__ lgE, int E) {
  int t = blockIdx.x * 256 + threadIdx.x;
  int e = t >> 3;
  if (e >= E) return;
  int h = t & 7;
  int d = dst[e];  // 8-lane broadcast

  const vf4* kk = (const vf4*)(k + (size_t)e * 128 + h * 16);
  const vf4* qq = (const vf4*)(q + (size_t)d * 128 + h * 16);
  vf4 a0 = __builtin_nontemporal_load(kk + 0);
  vf4 a1 = __builtin_nontemporal_load(kk + 1);
  vf4 a2 = __builtin_nontemporal_load(kk + 2);
  vf4 a3 = __builtin_nontemporal_load(kk + 3);
  vf4 b0 = qq[0], b1 = qq[1], b2 = qq[2], b3 = qq[3];
  float acc = a0.x * b0.x + a0.y * b0.y + a0.z * b0.z + a0.w * b0.w;
  acc += a1.x * b1.x + a1.y * b1.y + a1.z * b1.z + a1.w * b1.w;
  acc += a2.x * b2.x + a2.y * b2.y + a2.z * b2.z + a2.w * b2.w;
  acc += a3.x * b3.x + a3.y * b3.y + a3.z * b3.z + a3.w * b3.w;
  lgE[t] = acc * SCALE;  // edge-major, coalesced, L3-resident for pass B

  if (h == 0) {
    int pos = atomicAdd(&cursor[d], 1);
    if (pos < DCAP) eid[d * DCAP + pos] = e;
  }
}

// Pass B: persistent tiled gather. All LDS wave-private, no __syncthreads.
__global__ __launch_bounds__(256, 6) void gather_kernel(
    const float* __restrict__ v, const float* __restrict__ lgE,
    const int* __restrict__ cursor, const int* __restrict__ eid,
    float* __restrict__ out, int N, int E) {
  __shared__ int eidW[4][PN * DCAP];       // sorted edge ids per owned node
  __shared__ float miW[4][PN * HH * 2];    // per (node, head): m, 1/denom

  const int wave = threadIdx.x >> 6;
  const int lane = threadIdx.x & 63;
  const int gid = blockIdx.x * 4 + wave;   // global wave id, < NBLK*4
  const int n0 = gid * PN;
  const int nw = NBLK * 4;

  const char* vB = (const char*)v;
  const uint32_t vlane = (uint32_t)(lane * 12);
  const int j = lane >> 3;  // edge-slot residue (softmax phase)
  const int h = lane & 7;   // head (softmax phase)
  const int hc = lane >> 3; // head (accumulate phase; lane = channel)

  int degs[PN];

  // Stage + rank-sort eids (ascending), compute per-(node,head) m and 1/denom.
#pragma unroll
  for (int ln = 0; ln < PN; ++ln) {
    const int n = n0 + ln;
    int deg = 0;
    if (n < N) deg = min(cursor[n], DCAP);
    degs[ln] = deg;
    int* eb = &eidW[wave][ln * DCAP];
    if (lane < deg) eb[lane] = eid[n * DCAP + lane];  // deg<=64: one step
    // In-place rank sort: wave is lockstep, all rank-loop reads complete
    // before any lane executes the write. Edge ids are distinct (no ties).
    int x = 0, r = 0;
    if (lane < deg) {
      x = eb[lane];
      for (int t2 = 0; t2 < deg; ++t2) r += (eb[t2] < x) ? 1 : 0;
    }
    if (lane < deg) eb[r] = x;

    float m = -1e30f;
    for (int i = j; i < deg; i += 8) m = fmaxf(m, lgE[eb[i] * 8 + h]);
    m = fmaxf(m, __shfl_xor(m, 8, 64));
    m = fmaxf(m, __shfl_xor(m, 16, 64));
    m = fmaxf(m, __shfl_xor(m, 32, 64));
    float s = 0.f;
    for (int i = j; i < deg; i += 8) s += __expf(lgE[eb[i] * 8 + h] - m);
    s += __shfl_xor(s, 8, 64);
    s += __shfl_xor(s, 16, 64);
    s += __shfl_xor(s, 32, 64);
    const float inv = (s > 0.f) ? 1.0f / s : 0.f;  // deg==0 -> zeros
    if (j == 0) {
      miW[wave][(ln * HH + h) * 2 + 0] = m;
      miW[wave][(ln * HH + h) * 2 + 1] = inv;
    }
  }

  float a0[PN], a1[PN], a2[PN];
  int idx[PN];
#pragma unroll
  for (int ln = 0; ln < PN; ++ln) {
    a0[ln] = 0.f;
    a1[ln] = 0.f;
    a2[ln] = 0.f;
    idx[ln] = 0;
  }

  const int TR = (E + NTILE - 1) / NTILE;  // v rows per tile
  const int rpw = (TR + nw - 1) / nw;      // warm rows per wave

  // Stream this wave's slice of tile t (plain loads: must FILL the
  // memory-side L3, so no nontemporal hint).
  auto warm = [&](int t) {
    long tb = (long)t * TR;
    long te = tb + TR;
    if (te > E) te = E;
    long rs = tb + (long)gid * rpw;
    long re = rs + rpw;
    if (re > te) re = te;
    if (rs < re) {
      const char* p = vB + (size_t)rs * 768;
      const int nbytes = (int)(re - rs) * 768;
      float sink = 0.f;
      for (int off = lane * 16; off < nbytes; off += 64 * 16) {
        vf4 x4 = *(const vf4*)(p + off);
        sink += x4.x + x4.y + x4.z + x4.w;
      }
      asm volatile("" ::"v"(sink));  // keep the stream alive, no DCE
    }
  };

  warm(0);
  for (int t = 0; t < NTILE; ++t) {
    if (t + 1 < NTILE) warm(t + 1);  // pipeline: next tile streams into L3
    const int te = min(E, (t + 1) * TR);
#pragma unroll
    for (int ln = 0; ln < PN; ++ln) {
      const float m = miW[wave][(ln * HH + hc) * 2 + 0];
      const float inv = miW[wave][(ln * HH + hc) * 2 + 1];
      const int deg = degs[ln];
      int i = idx[ln];
      while (i < deg) {
        const int e = eidW[wave][ln * DCAP + i];  // LDS broadcast (uniform)
        if (e >= te) break;                       // sorted: rest in later tiles
        const float w = __expf(lgE[e * 8 + hc] - m) * inv;  // lgE: L3-hot
        const f3 vv = *(const f3*)(vB + (uint32_t)e * 768u + vlane);  // L3 hit
        a0[ln] += w * vv.x;
        a1[ln] += w * vv.y;
        a2[ln] += w * vv.z;
        ++i;
      }
      idx[ln] = i;
    }
  }

#pragma unroll
  for (int ln = 0; ln < PN; ++ln) {
    const int n = n0 + ln;
    if (n < N) {
      f3* op = (f3*)((char*)out + (size_t)n * 768 + vlane);
      op->x = a0[ln];
      op->y = a1[ln];
      op->z = a2[ln];
    }
  }
}

extern "C" void kernel_launch(void* const* d_in, const int* in_sizes, int n_in,
                              void* d_out, int out_size, void* d_ws,
                              size_t ws_size, hipStream_t stream) {
  const float* v = (const float*)d_in[0];
  const float* k = (const float*)d_in[1];
  const float* q = (const float*)d_in[2];
  const int* dst = (const int*)d_in[3];
  float* out = (float*)d_out;

  const int E = in_sizes[3];              // 800000
  const int N = in_sizes[2] / (HH * 16);  // 50000

  // Workspace: cursor[N] | eid[N*64] | lgE[E*8]  (~38.7 MB)
  char* ws = (char*)d_ws;
  size_t off = 0;
  auto take = [&](size_t bytes) {
    void* p = ws + off;
    off += (bytes + 255) & ~(size_t)255;
    return p;
  };
  int* cursor = (int*)take((size_t)N * sizeof(int));
  int* eid = (int*)take((size_t)N * DCAP * sizeof(int));
  float* lgE = (float*)take((size_t)E * HH * sizeof(float));

  hipMemsetAsync(cursor, 0, (size_t)N * sizeof(int), stream);
  edge_logits_kernel<<<(E * 8 + 255) / 256, 256, 0, stream>>>(k, q, dst, cursor,
                                                              eid, lgE, E);
  gather_kernel<<<NBLK, 256, 0, stream>>>(v, lgE, cursor, eid, out, N, E);
}

// Round 8
// 299.948 us; speedup vs baseline: 1.3735x; 1.3735x over previous
//
#include <hip/hip_runtime.h>
#include <hip/hip_bf16.h>

// v: [E, 64, 3] f32, k: [E, 8, 16] f32, q: [N, 8, 16] f32, dst: [E] i32
// out: [N, 64, 3] f32.  H=8 heads, T=16, 8 value channels/head, D=3.
//
// Structure (R6 champion + bf16 logits):
//  (A) edge-major: stream k at full BW (k random-gather would be 410MB at the
//      ~3TB/s random wall), gather q (25.6MB, L3-hot, 16x reuse), write
//      logits edge-major as bf16 (12.8MB, L2/L3-resident for pass C),
//      bucket-append eids.
//  (C) node-major: gather logits (16B/edge, cache-hot), LDS softmax, gather v
//      (614MB random 768B -- the one compulsory gather; measured wall
//      ~3TB/s), write out coalesced.
#define HH 8
#define CAPL 128     // per-wave LDS cache (Poisson(16): P(deg>128) ~ 1e-58)
#define BSTRIDE 256  // bucket capacity = max supported degree

static constexpr float SCALE = 0.08838834764831843f;  // 1/sqrt(8*16)

struct f3 {
  float x, y, z;
};  // stride-12 loads -> global_load_dwordx3

typedef float vf4 __attribute__((ext_vector_type(4)));

// Pass A: 8 lanes per edge. Stream k nontemporal; gather q; lgE[e*8+h]
// coalesced bf16 write; one bucket atomic per edge.
__global__ __launch_bounds__(256) void edge_logits_kernel(
    const float* __restrict__ k, const float* __restrict__ q,
    const int* __restrict__ dst, int* __restrict__ cursor,
    int* __restrict__ eid, __hip_bfloat16* __restrict__ lgE, int E) {
  int t = blockIdx.x * 256 + threadIdx.x;
  int e = t >> 3;
  if (e >= E) return;
  int h = t & 7;
  int d = dst[e];  // 8-lane broadcast

  const vf4* kk = (const vf4*)(k + (size_t)e * 128 + h * 16);
  const vf4* qq = (const vf4*)(q + (size_t)d * 128 + h * 16);
  vf4 a0 = __builtin_nontemporal_load(kk + 0);
  vf4 a1 = __builtin_nontemporal_load(kk + 1);
  vf4 a2 = __builtin_nontemporal_load(kk + 2);
  vf4 a3 = __builtin_nontemporal_load(kk + 3);
  vf4 b0 = qq[0], b1 = qq[1], b2 = qq[2], b3 = qq[3];
  float acc = a0.x * b0.x + a0.y * b0.y + a0.z * b0.z + a0.w * b0.w;
  acc += a1.x * b1.x + a1.y * b1.y + a1.z * b1.z + a1.w * b1.w;
  acc += a2.x * b2.x + a2.y * b2.y + a2.z * b2.z + a2.w * b2.w;
  acc += a3.x * b3.x + a3.y * b3.y + a3.z * b3.z + a3.w * b3.w;
  lgE[t] = __float2bfloat16(acc * SCALE);  // edge-major, coalesced, cache-hot

  if (h == 0) {
    int pos = atomicAdd(&cursor[d], 1);
    if (pos < BSTRIDE) eid[d * BSTRIDE + pos] = e;
  }
}

// Pass C: one wave per node. Bucket eids -> LDS; gather lgE (16B/edge,
// cache-hot); softmax in LDS; gather v (768B/edge, DRAM); write out.
// All LDS wave-private, no __syncthreads.
__global__ __launch_bounds__(256) void node_kernel(
    const float* __restrict__ v, const __hip_bfloat16* __restrict__ lgE,
    const int* __restrict__ cursor, const int* __restrict__ eid,
    float* __restrict__ out, int N) {
  __shared__ int eidL[4][CAPL];
  __shared__ float wL[4][CAPL * HH];

  int tid = threadIdx.x;
  int wave = tid >> 6;
  int lane = tid & 63;
  int node = blockIdx.x * 4 + wave;
  if (node >= N) return;

  int deg = min(cursor[node], BSTRIDE);
  int nl = min(deg, CAPL);
  const int* bucket = eid + node * BSTRIDE;
  const char* vB = (const char*)v;
  uint32_t vlane = (uint32_t)(lane * 12);

  for (int i = lane; i < nl; i += 64) eidL[wave][i] = bucket[i];
  // lockstep wave: LDS writes precede reads in program order, no barrier

  // Phase 1: gather raw logits -> LDS + per-head max. Lane i covers
  // (slot i>>3, head i&7); 64%8==0 so each lane's head is fixed: h=lane&7.
  float m = -1e30f;
  for (int i = lane; i < nl * 8; i += 64) {
    int e = eidL[wave][i >> 3];
    float lg = __bfloat162float(lgE[e * 8 + (i & 7)]);  // 16B/edge, cache-hot
    wL[wave][i] = lg;
    m = fmaxf(m, lg);
  }
  for (int i = CAPL * 8 + lane; i < deg * 8; i += 64) {  // overflow (never)
    int e = bucket[i >> 3];
    m = fmaxf(m, __bfloat162float(lgE[e * 8 + (i & 7)]));
  }
  m = fmaxf(m, __shfl_xor(m, 8, 64));
  m = fmaxf(m, __shfl_xor(m, 16, 64));
  m = fmaxf(m, __shfl_xor(m, 32, 64));

  // Phase 2: exp in place + denom.
  float s = 0.f;
  for (int i = lane; i < nl * 8; i += 64) {
    float ex = __expf(wL[wave][i] - m);
    wL[wave][i] = ex;
    s += ex;
  }
  for (int i = CAPL * 8 + lane; i < deg * 8; i += 64) {  // overflow (never)
    int e = bucket[i >> 3];
    s += __expf(__bfloat162float(lgE[e * 8 + (i & 7)]) - m);
  }
  s += __shfl_xor(s, 8, 64);
  s += __shfl_xor(s, 16, 64);
  s += __shfl_xor(s, 32, 64);
  float inv = (s > 0.f) ? 1.0f / s : 0.f;  // deg==0 -> zeros, not NaN

  // Phase 3: channel accumulation. Lane owns channel `lane`, head hc=lane>>3.
  // Unroll x4: 4 independent dwordx3 v-loads in flight.
  int hc = lane >> 3;
  float minv = __shfl(inv, hc, 64);
  float m_c = __shfl(m, hc, 64);
  float a0 = 0.f, a1 = 0.f, a2 = 0.f;
  int i = 0;
  for (; i + 4 <= nl; i += 4) {
    int e0 = eidL[wave][i + 0];
    int e1 = eidL[wave][i + 1];
    int e2 = eidL[wave][i + 2];
    int e3 = eidL[wave][i + 3];
    float w0 = wL[wave][(i + 0) * 8 + hc];
    float w1 = wL[wave][(i + 1) * 8 + hc];
    float w2 = wL[wave][(i + 2) * 8 + hc];
    float w3 = wL[wave][(i + 3) * 8 + hc];
    f3 v0 = *(const f3*)(vB + (uint32_t)e0 * 768u + vlane);
    f3 v1 = *(const f3*)(vB + (uint32_t)e1 * 768u + vlane);
    f3 v2 = *(const f3*)(vB + (uint32_t)e2 * 768u + vlane);
    f3 v3 = *(const f3*)(vB + (uint32_t)e3 * 768u + vlane);
    a0 += w0 * v0.x + w1 * v1.x + w2 * v2.x + w3 * v3.x;
    a1 += w0 * v0.y + w1 * v1.y + w2 * v2.y + w3 * v3.y;
    a2 += w0 * v0.z + w1 * v1.z + w2 * v2.z + w3 * v3.z;
  }
  for (; i < nl; ++i) {
    int e = eidL[wave][i];
    float w = wL[wave][i * 8 + hc];
    f3 vv = *(const f3*)(vB + (uint32_t)e * 768u + vlane);
    a0 += w * vv.x;
    a1 += w * vv.y;
    a2 += w * vv.z;
  }
  for (; i < deg; ++i) {  // overflow (never in practice)
    int e = bucket[i];
    float w = __expf(__bfloat162float(lgE[e * 8 + hc]) - m_c);  // unnormalized
    f3 vv = *(const f3*)(vB + (uint32_t)e * 768u + vlane);
    a0 += w * vv.x;
    a1 += w * vv.y;
    a2 += w * vv.z;
  }
  a0 *= minv;
  a1 *= minv;
  a2 *= minv;

  f3* op = (f3*)((char*)out + (uint32_t)node * 768u + vlane);
  op->x = a0;
  op->y = a1;
  op->z = a2;
}

extern "C" void kernel_launch(void* const* d_in, const int* in_sizes, int n_in,
                              void* d_out, int out_size, void* d_ws,
                              size_t ws_size, hipStream_t stream) {
  const float* v = (const float*)d_in[0];
  const float* k = (const float*)d_in[1];
  const float* q = (const float*)d_in[2];
  const int* dst = (const int*)d_in[3];
  float* out = (float*)d_out;

  const int E = in_sizes[3];              // 800000
  const int N = in_sizes[2] / (HH * 16);  // 50000

  // Workspace: cursor[N] | eid[N*256] | lgE[E*8] bf16
  char* ws = (char*)d_ws;
  size_t off = 0;
  auto take = [&](size_t bytes) {
    void* p = ws + off;
    off += (bytes + 255) & ~(size_t)255;
    return p;
  };
  int* cursor = (int*)take((size_t)N * sizeof(int));
  int* eid = (int*)take((size_t)N * BSTRIDE * sizeof(int));
  __hip_bfloat16* lgE =
      (__hip_bfloat16*)take((size_t)E * HH * sizeof(__hip_bfloat16));

  hipMemsetAsync(cursor, 0, (size_t)N * sizeof(int), stream);
  edge_logits_kernel<<<(E * 8 + 255) / 256, 256, 0, stream>>>(k, q, dst, cursor,
                                                              eid, lgE, E);
  node_kernel<<<(N + 3) / 4, 256, 0, stream>>>(v, lgE, cursor, eid, out, N);
}